// Round 3
// baseline (150.267 us; speedup 1.0000x reference)
//
#include <hip/hip_runtime.h>
#include <math.h>

#define B_ 4
#define S_ 2048
#define D_ 128
#define EPSF 1e-5f
#define BN 128
#define PSB 272   // Ps row stride in bytes: 16B-aligned rows

typedef __attribute__((ext_vector_type(8))) short short8;
typedef __attribute__((ext_vector_type(4))) float f32x4;

static __device__ __forceinline__ unsigned short f2bf(float f) {
    unsigned u = __float_as_uint(f);
    return (unsigned short)((u + 0x7fffu + ((u >> 16) & 1u)) >> 16);
}

static __device__ __forceinline__ void gload_lds16(const void* g, void* l) {
    __builtin_amdgcn_global_load_lds((const __attribute__((address_space(1))) unsigned*)g,
                                     (__attribute__((address_space(3))) unsigned*)l, 16, 0, 0);
}

// ===================== pre-pass kernels (shared by both paths) =====================
// ws bytes: [0,32K) qn, [32K,64K) kn, [64K,96K) lws, [96K,160K) qng, [160K,224K) kng,
//           [224K..) Qb(2M) Kb(2M) Vtb(2M)

__global__ __launch_bounds__(256) void convqk_kernel(const float* __restrict__ q,
                                                     const float* __restrict__ k,
                                                     const float* __restrict__ cp,
                                                     float* __restrict__ qn, float* __restrict__ kn,
                                                     float* __restrict__ lws,
                                                     float2* __restrict__ qng, float2* __restrict__ kng,
                                                     unsigned* __restrict__ Qb, unsigned* __restrict__ Kb) {
    int row = blockIdx.x * 4 + (threadIdx.x >> 6);   // one wave per row, 16384 rows
    int lane = threadIdx.x & 63;
    const int NR = B_ * S_;
    const float cc = cp[0];
    bool isQ = row < NR;
    int r = isQ ? row : row - NR;
    float2 v = ((const float2*)(isQ ? q : k))[(size_t)r * 64 + lane];
    unsigned pk = (unsigned)f2bf(v.x) | ((unsigned)f2bf(v.y) << 16);
    float nrm = v.x * v.x + v.y * v.y;
#pragma unroll
    for (int m = 1; m <= 32; m <<= 1) nrm += __shfl_xor(nrm, m, 64);
    if (isQ) {
        Qb[(size_t)r * 64 + lane] = pk;              // plain row-major
        if (lane == 0) {
            qn[r] = nrm;
            qng[r] = make_float2(nrm, 2.f * cc * __builtin_amdgcn_rcpf(1.f - cc * nrm));
        }
        if (lane == 1) lws[r] = 0.f;                 // zero l accumulator (fallback path)
    } else {
        int c = lane >> 2;                           // 16B chunk index 0..15
        int cs = c ^ (r & 7);                        // bake LDS bank swizzle into global layout
        Kb[(size_t)r * 64 + cs * 4 + (lane & 3)] = pk;
        if (lane == 0) {
            kn[r] = nrm;
            kng[r] = make_float2(nrm, __builtin_amdgcn_rcpf(1.f - cc * nrm));
        }
    }
}

__global__ __launch_bounds__(256) void convv_kernel(const float* __restrict__ v, uint4* __restrict__ Vtb) {
    __shared__ unsigned short Vs[128 * 132];
    int b = blockIdx.x >> 4;
    int t = blockIdx.x & 15;
    int tid = threadIdx.x;
    const float* src = v + ((size_t)b * S_ + t * 128) * D_;
    int d4 = tid & 31, key0 = tid >> 5;
#pragma unroll
    for (int it = 0; it < 16; ++it) {
        int key = key0 + it * 8;
        float4 f = *(const float4*)(src + (size_t)key * D_ + d4 * 4);
        unsigned short* dst = &Vs[key * 132 + d4 * 4];
        dst[0] = f2bf(f.x); dst[1] = f2bf(f.y); dst[2] = f2bf(f.z); dst[3] = f2bf(f.w);
    }
    __syncthreads();
    uint4* tile = Vtb + (size_t)blockIdx.x * (128 * 16);   // [tile][d=128][16 x 16B chunks]
    int d = tid & 127;
    int cl = tid >> 7;
#pragma unroll
    for (int it = 0; it < 8; ++it) {
        int c = cl + it * 2;
        int kb = c * 8;
        unsigned short e0 = Vs[(kb + 0) * 132 + d], e1 = Vs[(kb + 1) * 132 + d];
        unsigned short e2 = Vs[(kb + 2) * 132 + d], e3 = Vs[(kb + 3) * 132 + d];
        unsigned short e4 = Vs[(kb + 4) * 132 + d], e5 = Vs[(kb + 5) * 132 + d];
        unsigned short e6 = Vs[(kb + 6) * 132 + d], e7 = Vs[(kb + 7) * 132 + d];
        uint4 o;
        o.x = (unsigned)e0 | ((unsigned)e1 << 16);
        o.y = (unsigned)e2 | ((unsigned)e3 << 16);
        o.z = (unsigned)e4 | ((unsigned)e5 << 16);
        o.w = (unsigned)e6 | ((unsigned)e7 << 16);
        tile[d * 16 + (c ^ (d & 7))] = o;
    }
}

// ===================== v4: fully fused full-row kernel =====================
// One 1024-thread block per 32 q-rows (grid 256, 1 block/CU, 16 waves). 16 iterations of
// 128-key tiles with the proven double-buffered pipeline (K+V staged at iter top, drained
// by barrier A under QK+dist). P kept in registers (bf16-packed, statically indexed via
// full unroll). At the end: l reduction, direct normalized fp32 W write, O normalize +
// exp-map + hout write. No Pws/Opart round-trip, no wnorm2/hepi kernels.
//
// LDS map (142336 B total):
//   Ks[2]  @      0 / 32768   (128 key-rows x 256B each, swizzle baked in Kb)
//   Vt[2]  @  65536 / 98304   (128 d-rows x 256B each, swizzle baked in Vtb)
//   Ps     @ 131072           (32 rows x 272B bf16)
//   yg[2]  @ 139776 / 140800  (128 float2 each: {yn, gy})
//   xr     @ 141824           (32 float2: {xn, rx})
//   l_row  @ 142080           (32 f32)
//   nsq_s  @ 142208           (32 f32)

__global__ __launch_bounds__(1024, 4) void hattn4_kernel(
    const unsigned short* __restrict__ Qb, const char* __restrict__ Kb, const char* __restrict__ Vtb,
    const float2* __restrict__ qng, const float2* __restrict__ kng,
    const float* __restrict__ cp, const float* __restrict__ betap, const float* __restrict__ biasp,
    float* __restrict__ hout, float* __restrict__ wout) {

    __shared__ __align__(1024) char smem[142336];
    char* PsB = smem + 131072;
    float* l_row = (float*)(smem + 142080);
    float* nsq_s = (float*)(smem + 142208);

    const int tid = threadIdx.x;
    const int lane = tid & 63, wave = tid >> 6;      // 16 waves
    const int wm = wave & 1, wn = wave >> 1;         // wm: 16-row half; wn: 16-col / 16-d slice (0..7)
    const int lm = lane & 15, quad = lane >> 4;

    int xcd = blockIdx.x & 7;                        // group batches per XCD for L2 locality
    int b = xcd >> 1;
    int rb = (blockIdx.x >> 3) * 2 + (xcd & 1);      // 0..63
    int s0 = rb * 32;
    const size_t bS = (size_t)b * S_;

    const float beta = betap[0], bias = biasp[0];
    const float cc = cp[0];
    const float beta_pos = fmaxf(beta, 0.f) + log1pf(__expf(-fabsf(beta)));
    const float sqrt_c = sqrtf(cc);
    const float bneg = -beta_pos / sqrt_c;           // p = 2^(bneg*log2(w) + bias2)
    const float bias2 = -bias * 1.442695040888963f;
    const float onepe = 1.f + EPSF;

    const char* KbBase = Kb + bS * 256;
    const char* VtBase = Vtb + (size_t)b * 16 * 32768;

    // ---- prologue: stage tile 0 into buffer 0 (full-wave gload_lds), tables via plain ops ----
    {
#pragma unroll
        for (int j = 0; j < 2; ++j) {
            int m = tid + j * 1024;
            gload_lds16(KbBase + m * 16, smem + m * 16);
            gload_lds16(VtBase + m * 16, smem + 65536 + m * 16);
        }
        if (tid < 128) {
            float2 y = kng[bS + tid];
            *(float2*)(smem + 139776 + tid * 8) = y;
        } else if (tid < 160) {
            float2 x = qng[bS + s0 + (tid - 128)];
            *(float2*)(smem + 141824 + (tid - 128) * 8) = x;
        } else if (tid < 192) {
            l_row[tid - 160] = 0.f;
        } else if (tid < 224) {
            nsq_s[tid - 192] = 0.f;
        }
    }

    // Q A-frags in registers (A: m=lane&15, k=quad*8+j)
    short8 aq[4];
    {
        const unsigned short* qrow = Qb + (bS + s0 + wm * 16 + lm) * D_;
#pragma unroll
        for (int ks = 0; ks < 4; ++ks)
            aq[ks] = *(const short8*)(qrow + ks * 32 + quad * 8);
    }

    f32x4 o = {0.f, 0.f, 0.f, 0.f};
    float lacc[4] = {0.f, 0.f, 0.f, 0.f};
    unsigned pst[32];                                // bf16-packed P, static-indexed (full unroll)

    __syncthreads();   // prologue staging drained (vmcnt(0)+lgkmcnt(0) implicit)

    int p = 0;
    const int n0 = wn * 16 + lm;                     // key col (QK) / d index (PV)
#pragma unroll
    for (int it = 0; it < 16; ++it) {
        char* KsC = smem + p * 32768;
        char* VtC = smem + 65536 + p * 32768;
        const char* YGC = smem + 139776 + p * 1024;

        // ---- issue next K+V tiles into back buffers + kng load to regs (hidden under QK+dist) ----
        float2 ygn;
        if (it < 15) {
            const char* ks = KbBase + (size_t)(it + 1) * 32768;
            const char* vs = VtBase + (size_t)(it + 1) * 32768;
            char* kd = smem + (p ^ 1) * 32768;
            char* vd = smem + 65536 + (p ^ 1) * 32768;
#pragma unroll
            for (int j = 0; j < 2; ++j) {
                int off = (tid + j * 1024) * 16;
                gload_lds16(ks + off, kd + off);
                gload_lds16(vs + off, vd + off);
            }
            if (tid < 128) ygn = kng[bS + (size_t)(it + 1) * 128 + tid];
        }

        // ---- S = Q K^T (wave tile 16x16 of the 32x128 block tile) ----
        f32x4 acc = {0.f, 0.f, 0.f, 0.f};
#pragma unroll
        for (int ks = 0; ks < 4; ++ks) {
            int c = ks * 4 + quad;
            short8 bk = *(const short8*)(KsC + n0 * 256 + ((c ^ (n0 & 7)) * 16));
            acc = __builtin_amdgcn_mfma_f32_16x16x32_bf16(aq[ks], bk, acc, 0, 0, 0);
        }

        // ---- dist -> p = exp2(bneg*log2(arg+sqrt(arg^2-1)) + bias2), unnormalized ----
        {
            float2 yg = *(const float2*)(YGC + n0 * 8);
            unsigned pw0 = 0, pw1 = 0;
#pragma unroll
            for (int r = 0; r < 4; ++r) {
                int row = wm * 16 + quad * 4 + r;    // C/D layout: row=(lane>>4)*4+reg
                float2 xr = *(const float2*)(smem + 141824 + row * 8);
                float diff = fmaf(-2.f, acc[r], xr.x + yg.x);
                float arg = fmaf(diff * yg.y, xr.y, 1.f);
                arg = fmaxf(arg, onepe);
                float w = arg + sqrtf(fmaf(arg, arg, -1.f));
                float pv = __builtin_amdgcn_exp2f(fmaf(bneg, __builtin_amdgcn_logf(w), bias2));
                unsigned short pb = f2bf(pv);
                *(unsigned short*)(PsB + row * PSB + n0 * 2) = pb;
                lacc[r] += pv;
                if (r == 0) pw0 = pb;
                else if (r == 1) pw0 |= (unsigned)pb << 16;
                else if (r == 2) pw1 = pb;
                else pw1 |= (unsigned)pb << 16;
            }
            pst[it * 2] = pw0;
            pst[it * 2 + 1] = pw1;
        }
        __syncthreads();   // A: Ps visible; K/V back buffers staged (implicit vmcnt drain)

        // ---- store next-iter key norms to back LDS table (visible after barrier B) ----
        if (it < 15 && tid < 128) *(float2*)(smem + 139776 + (p ^ 1) * 1024 + tid * 8) = ygn;

        // ---- O += P V (wave tile 16 rows x 16 d, K=128 keys) ----
#pragma unroll
        for (int ks = 0; ks < 4; ++ks) {
            short8 ap = *(const short8*)(PsB + (wm * 16 + lm) * PSB + (ks * 32 + quad * 8) * 2);
            int c = ks * 4 + quad;
            short8 vv = *(const short8*)(VtC + n0 * 256 + ((c ^ (n0 & 7)) * 16));
            o = __builtin_amdgcn_mfma_f32_16x16x32_bf16(ap, vv, o, 0, 0, 0);
        }
        __syncthreads();   // B: Ps/Ks/Vt[p] readers done; yg store visible
        p ^= 1;
    }

    // ---- l reduction: per-thread register sums -> 16-lane shfl -> LDS atomics ----
#pragma unroll
    for (int r = 0; r < 4; ++r) {
        float s = lacc[r];
#pragma unroll
        for (int m = 1; m <= 8; m <<= 1) s += __shfl_xor(s, m, 64);
        if (lm == 0) atomicAdd(&l_row[wm * 16 + quad * 4 + r], s);
    }
    __syncthreads();

    float linv[4];
#pragma unroll
    for (int r = 0; r < 4; ++r) linv[r] = 1.f / l_row[wm * 16 + quad * 4 + r];

    // ---- O normalize + exp-map + hout ----
#pragma unroll
    for (int r = 0; r < 4; ++r) {
        float x = o[r] * linv[r];
        o[r] = x;
        float np = x * x;
#pragma unroll
        for (int m = 1; m <= 8; m <<= 1) np += __shfl_xor(np, m, 64);
        if (lm == 0) atomicAdd(&nsq_s[wm * 16 + quad * 4 + r], np);
    }
    __syncthreads();
#pragma unroll
    for (int r = 0; r < 4; ++r) {
        int row = wm * 16 + quad * 4 + r;
        float vn = fmaxf(sqrtf(nsq_s[row]), EPSF);
        float a = sqrt_c * vn;
        float th = 1.f - 2.f / (__expf(2.f * a) + 1.f);  // tanh(a)
        float sc = th / a;                                // tanh(sqrt_c*vn)/(sqrt_c*vn)
        hout[(bS + s0 + row) * D_ + n0] = o[r] * sc;
    }

    // ---- direct normalized fp32 W write from register-held P ----
    {
        const size_t wbase = (bS + s0) * (size_t)S_;
        const int row0 = wm * 16 + quad * 4;
#pragma unroll
        for (int it = 0; it < 16; ++it) {
            unsigned pw0 = pst[it * 2], pw1 = pst[it * 2 + 1];
            float p0 = __uint_as_float(pw0 << 16) * linv[0];
            float p1 = __uint_as_float(pw0 & 0xffff0000u) * linv[1];
            float p2 = __uint_as_float(pw1 << 16) * linv[2];
            float p3 = __uint_as_float(pw1 & 0xffff0000u) * linv[3];
            size_t cg = wbase + (size_t)it * 128 + n0;
            wout[cg + (size_t)(row0 + 0) * S_] = p0;
            wout[cg + (size_t)(row0 + 1) * S_] = p1;
            wout[cg + (size_t)(row0 + 2) * S_] = p2;
            wout[cg + (size_t)(row0 + 3) * S_] = p3;
        }
    }
}

// ===================== round-2 path (proven, ws fallback) =====================

__global__ __launch_bounds__(512, 2) void hattn_kernel(
    const unsigned short* __restrict__ Qb, const char* __restrict__ Kb, const char* __restrict__ Vtb,
    const float* __restrict__ qn, const float* __restrict__ kn,
    const float* __restrict__ cp, const float* __restrict__ betap, const float* __restrict__ biasp,
    float* __restrict__ lws, float* __restrict__ houtg, float* __restrict__ woutg) {

    __shared__ __align__(1024) char smem[75136];
    char* KsB = smem;
    char* VtB = smem + 32768;
    char* PsB = smem + 65536;
    float* kn_s  = (float*)(smem + 74240);
    float* qn_s  = (float*)(smem + 74752);
    float* l_row = (float*)(smem + 74880);
    float* nsq_s = (float*)(smem + 75008);

    const int tid = threadIdx.x;
    const int lane = tid & 63, wave = tid >> 6;
    const int wm = wave & 1, wn = wave >> 1;
    const int lm = lane & 15, quad = lane >> 4;

    int xcd = blockIdx.x & 7;
    int b = xcd >> 1;
    int rb = (blockIdx.x >> 3) * 2 + (xcd & 1);
    int s0 = rb * 32;
    const size_t bS = (size_t)b * S_;

    const float cc = cp[0], beta = betap[0], bias = biasp[0];
    const float beta_pos = fmaxf(beta, 0.f) + log1pf(__expf(-fabsf(beta)));
    const float sqrt_c = sqrtf(cc);
    const float inv_sqrt_c = 1.f / sqrt_c;

    if (tid < 32) {
        qn_s[tid] = qn[bS + s0 + tid];
        l_row[tid] = 0.f;
        nsq_s[tid] = 0.f;
    }

    short8 aq[4];
    {
        const unsigned short* qrow = Qb + (bS + s0 + wm * 16 + lm) * D_;
#pragma unroll
        for (int ks = 0; ks < 4; ++ks)
            aq[ks] = *(const short8*)(qrow + ks * 32 + quad * 8);
    }

    f32x4 o0 = {0.f, 0.f, 0.f, 0.f}, o1 = {0.f, 0.f, 0.f, 0.f};

    const char* KbBase = Kb + bS * 256;
    const char* VtBase = Vtb + (size_t)b * 16 * 32768;

    for (int t = 0; t < S_ / BN; ++t) {
        int t0 = t * BN;
        __syncthreads();
        {
            const uint4* ksrc = (const uint4*)(KbBase + (size_t)t0 * 256);
            const uint4* vsrc = (const uint4*)(VtBase + (size_t)t * 32768);
            uint4* kd = (uint4*)KsB;
            uint4* vd = (uint4*)VtB;
#pragma unroll
            for (int i = 0; i < 4; ++i) {
                kd[tid + i * 512] = ksrc[tid + i * 512];
                vd[tid + i * 512] = vsrc[tid + i * 512];
            }
            if (tid < BN) kn_s[tid] = kn[bS + t0 + tid];
        }
        __syncthreads();

        f32x4 acc0 = {0.f, 0.f, 0.f, 0.f}, acc1 = {0.f, 0.f, 0.f, 0.f};
#pragma unroll
        for (int ks = 0; ks < 4; ++ks) {
            int n0 = wn * 32 + lm;
            int c = ks * 4 + quad;
            short8 b0 = *(const short8*)(KsB + n0 * 256 + ((c ^ (n0 & 7)) * 16));
            int n1 = n0 + 16;
            short8 b1 = *(const short8*)(KsB + n1 * 256 + ((c ^ (n1 & 7)) * 16));
            acc0 = __builtin_amdgcn_mfma_f32_16x16x32_bf16(aq[ks], b0, acc0, 0, 0, 0);
            acc1 = __builtin_amdgcn_mfma_f32_16x16x32_bf16(aq[ks], b1, acc1, 0, 0, 0);
        }

        float lp[4];
#pragma unroll
        for (int r = 0; r < 4; ++r) {
            int row = wm * 16 + quad * 4 + r;
            float xn = qn_s[row];
            float fx = 1.f - cc * xn;
            float p0, p1;
#pragma unroll
            for (int nt = 0; nt < 2; ++nt) {
                int col = wn * 32 + nt * 16 + lm;
                float dot = (nt == 0) ? acc0[r] : acc1[r];
                float yn = kn_s[col];
                float diff = xn - 2.f * dot + yn;
                float den = fmaxf(fx * (1.f - cc * yn), EPSF);
                float arg = fmaf(2.f * cc * diff, __builtin_amdgcn_rcpf(den), 1.f);
                arg = fmaxf(arg, 1.f + EPSF);
                float dist = __logf(arg + sqrtf(arg * arg - 1.f)) * inv_sqrt_c;
                float p = __expf(fmaf(-beta_pos, dist, -bias));
                woutg[(bS + s0 + row) * S_ + t0 + col] = p;
                *(unsigned short*)(PsB + row * PSB + col * 2) = f2bf(p);
                if (nt == 0) p0 = p; else p1 = p;
            }
            lp[r] = p0 + p1;
        }
#pragma unroll
        for (int r = 0; r < 4; ++r) {
            float s = lp[r];
#pragma unroll
            for (int m = 1; m <= 8; m <<= 1) s += __shfl_xor(s, m, 64);
            if (lm == 0) atomicAdd(&l_row[wm * 16 + quad * 4 + r], s);
        }
        __syncthreads();

#pragma unroll
        for (int ks = 0; ks < 4; ++ks) {
            short8 ap = *(const short8*)(PsB + (wm * 16 + lm) * PSB + (ks * 32 + quad * 8) * 2);
            int d0 = wn * 32 + lm;
            int c = ks * 4 + quad;
            short8 v0 = *(const short8*)(VtB + d0 * 256 + ((c ^ (d0 & 7)) * 16));
            int d1 = d0 + 16;
            short8 v1 = *(const short8*)(VtB + d1 * 256 + ((c ^ (d1 & 7)) * 16));
            o0 = __builtin_amdgcn_mfma_f32_16x16x32_bf16(ap, v0, o0, 0, 0, 0);
            o1 = __builtin_amdgcn_mfma_f32_16x16x32_bf16(ap, v1, o1, 0, 0, 0);
        }
    }
    __syncthreads();

    float xs0[4], xs1[4];
#pragma unroll
    for (int r = 0; r < 4; ++r) {
        int row = wm * 16 + quad * 4 + r;
        float linv = __builtin_amdgcn_rcpf(l_row[row]);
        float x0 = o0[r] * linv, x1 = o1[r] * linv;
        xs0[r] = x0; xs1[r] = x1;
        float np = x0 * x0 + x1 * x1;
#pragma unroll
        for (int m = 1; m <= 8; m <<= 1) np += __shfl_xor(np, m, 64);
        if (lm == 0) atomicAdd(&nsq_s[row], np);
    }
    if (tid < 32) lws[bS + s0 + tid] = l_row[tid];
    __syncthreads();
#pragma unroll
    for (int r = 0; r < 4; ++r) {
        int row = wm * 16 + quad * 4 + r;
        float vn = fmaxf(sqrtf(nsq_s[row]), EPSF);
        float a = sqrt_c * vn;
        float th = 1.f - 2.f * __builtin_amdgcn_rcpf(__expf(2.f * a) + 1.f);
        float sc = th / a;
        houtg[(bS + s0 + row) * D_ + wn * 32 + lm] = xs0[r] * sc;
        houtg[(bS + s0 + row) * D_ + wn * 32 + 16 + lm] = xs1[r] * sc;
    }
}

__global__ __launch_bounds__(256) void wnorm_kernel(float* __restrict__ w,
                                                    const float* __restrict__ lws) {
    size_t idx = (size_t)blockIdx.x * 256 + threadIdx.x;
    int row = (int)(idx >> 9);
    float linv = 1.f / lws[row];
    float4* p = (float4*)w + idx;
    float4 v = *p;
    v.x *= linv; v.y *= linv; v.z *= linv; v.w *= linv;
    *p = v;
}

// ===================== launch =====================

extern "C" void kernel_launch(void* const* d_in, const int* in_sizes, int n_in,
                              void* d_out, int out_size, void* d_ws, size_t ws_size,
                              hipStream_t stream) {
    const float* q    = (const float*)d_in[0];
    const float* k    = (const float*)d_in[1];
    const float* v    = (const float*)d_in[2];
    const float* c    = (const float*)d_in[3];
    const float* beta = (const float*)d_in[4];
    const float* ab   = (const float*)d_in[5];

    float* out  = (float*)d_out;
    float* hout = out;                          // (B,S,D)
    float* wout = out + (size_t)B_ * S_ * D_;   // (B,S,S)

    float* qn  = (float*)d_ws;
    float* kn  = qn + B_ * S_;
    float* lws = kn + B_ * S_;
    char*  wsb = (char*)d_ws;
    const size_t QG_OFF = 98304;
    const size_t KG_OFF = QG_OFF + 65536;
    const size_t QB_OFF = KG_OFF + 65536;       // 229376
    const size_t KB_OFF = QB_OFF + 2097152;
    const size_t VT_OFF = KB_OFF + 2097152;
    const size_t NEED1  = VT_OFF + 2097152;

    float2*  qng = (float2*)(wsb + QG_OFF);
    float2*  kng = (float2*)(wsb + KG_OFF);
    unsigned* Qb = (unsigned*)(wsb + QB_OFF);
    unsigned* Kb = (unsigned*)(wsb + KB_OFF);
    uint4*   Vtb = (uint4*)(wsb + VT_OFF);

    if (ws_size >= NEED1) {
        convqk_kernel<<<4096, 256, 0, stream>>>(q, k, c, qn, kn, lws, qng, kng, Qb, Kb);
        convv_kernel<<<64, 256, 0, stream>>>(v, Vtb);
        hattn4_kernel<<<256, 1024, 0, stream>>>((const unsigned short*)Qb, (const char*)Kb,
                                                (const char*)Vtb, qng, kng, c, beta, ab,
                                                hout, wout);
    } else {
        convqk_kernel<<<4096, 256, 0, stream>>>(q, k, c, qn, kn, lws, qng, kng, Qb, Kb);
        convv_kernel<<<64, 256, 0, stream>>>(v, Vtb);
        hattn_kernel<<<256, 512, 0, stream>>>((const unsigned short*)Qb, (const char*)Kb,
                                              (const char*)Vtb, qn, kn, c, beta, ab,
                                              lws, hout, wout);
        wnorm_kernel<<<(B_ * S_ * S_ / 4) / 256, 256, 0, stream>>>(wout, lws);
    }
}

// Round 4
// 147.631 us; speedup vs baseline: 1.0179x; 1.0179x over previous
//
#include <hip/hip_runtime.h>
#include <math.h>

#define B_ 4
#define S_ 2048
#define D_ 128
#define EPSF 1e-5f
#define BN 128
#define PSB 272   // Ps row stride in bytes: 16B-aligned rows

typedef __attribute__((ext_vector_type(8))) short short8;
typedef __attribute__((ext_vector_type(4))) float f32x4;

static __device__ __forceinline__ unsigned short f2bf(float f) {
    unsigned u = __float_as_uint(f);
    return (unsigned short)((u + 0x7fffu + ((u >> 16) & 1u)) >> 16);
}

static __device__ __forceinline__ void gload_lds16(const void* g, void* l) {
    __builtin_amdgcn_global_load_lds((const __attribute__((address_space(1))) unsigned*)g,
                                     (__attribute__((address_space(3))) unsigned*)l, 16, 0, 0);
}

// ===================== pre-pass kernels (shared by both paths) =====================
// ws bytes: [0,32K) qn, [32K,64K) kn, [64K,96K) lws, [96K,160K) qng, [160K,224K) kng,
//           [224K..) Qb(2M) Kb(2M) Vtb(2M) [Pws 33.5M]

__global__ __launch_bounds__(256) void convqk_kernel(const float* __restrict__ q,
                                                     const float* __restrict__ k,
                                                     const float* __restrict__ cp,
                                                     float* __restrict__ qn, float* __restrict__ kn,
                                                     float* __restrict__ lws,
                                                     float2* __restrict__ qng, float2* __restrict__ kng,
                                                     unsigned* __restrict__ Qb, unsigned* __restrict__ Kb) {
    int row = blockIdx.x * 4 + (threadIdx.x >> 6);   // one wave per row, 16384 rows
    int lane = threadIdx.x & 63;
    const int NR = B_ * S_;
    const float cc = cp[0];
    bool isQ = row < NR;
    int r = isQ ? row : row - NR;
    float2 v = ((const float2*)(isQ ? q : k))[(size_t)r * 64 + lane];
    unsigned pk = (unsigned)f2bf(v.x) | ((unsigned)f2bf(v.y) << 16);
    float nrm = v.x * v.x + v.y * v.y;
#pragma unroll
    for (int m = 1; m <= 32; m <<= 1) nrm += __shfl_xor(nrm, m, 64);
    if (isQ) {
        Qb[(size_t)r * 64 + lane] = pk;              // plain row-major
        if (lane == 0) {
            qn[r] = nrm;
            qng[r] = make_float2(nrm, 2.f * cc * __builtin_amdgcn_rcpf(1.f - cc * nrm));
        }
        if (lane == 1) lws[r] = 0.f;                 // zero l accumulator (fallback path)
    } else {
        int c = lane >> 2;                           // 16B chunk index 0..15
        int cs = c ^ (r & 7);                        // bake LDS bank swizzle into global layout
        Kb[(size_t)r * 64 + cs * 4 + (lane & 3)] = pk;
        if (lane == 0) {
            kn[r] = nrm;
            kng[r] = make_float2(nrm, __builtin_amdgcn_rcpf(1.f - cc * nrm));
        }
    }
}

__global__ __launch_bounds__(256) void convv_kernel(const float* __restrict__ v, uint4* __restrict__ Vtb) {
    __shared__ unsigned short Vs[128 * 132];
    int b = blockIdx.x >> 4;
    int t = blockIdx.x & 15;
    int tid = threadIdx.x;
    const float* src = v + ((size_t)b * S_ + t * 128) * D_;
    int d4 = tid & 31, key0 = tid >> 5;
#pragma unroll
    for (int it = 0; it < 16; ++it) {
        int key = key0 + it * 8;
        float4 f = *(const float4*)(src + (size_t)key * D_ + d4 * 4);
        unsigned short* dst = &Vs[key * 132 + d4 * 4];
        dst[0] = f2bf(f.x); dst[1] = f2bf(f.y); dst[2] = f2bf(f.z); dst[3] = f2bf(f.w);
    }
    __syncthreads();
    uint4* tile = Vtb + (size_t)blockIdx.x * (128 * 16);   // [tile][d=128][16 x 16B chunks]
    int d = tid & 127;
    int cl = tid >> 7;
#pragma unroll
    for (int it = 0; it < 8; ++it) {
        int c = cl + it * 2;
        int kb = c * 8;
        unsigned short e0 = Vs[(kb + 0) * 132 + d], e1 = Vs[(kb + 1) * 132 + d];
        unsigned short e2 = Vs[(kb + 2) * 132 + d], e3 = Vs[(kb + 3) * 132 + d];
        unsigned short e4 = Vs[(kb + 4) * 132 + d], e5 = Vs[(kb + 5) * 132 + d];
        unsigned short e6 = Vs[(kb + 6) * 132 + d], e7 = Vs[(kb + 7) * 132 + d];
        uint4 o;
        o.x = (unsigned)e0 | ((unsigned)e1 << 16);
        o.y = (unsigned)e2 | ((unsigned)e3 << 16);
        o.z = (unsigned)e4 | ((unsigned)e5 << 16);
        o.w = (unsigned)e6 | ((unsigned)e7 << 16);
        tile[d * 16 + (c ^ (d & 7))] = o;
    }
}

// ===================== v5: fused full-row kernel, P via global bf16 staging =====================
// One 1024-thread block per 32 q-rows (grid 256, 1 block/CU, 16 waves = 4/SIMD). 16 iterations
// of 128-key tiles, K+V double-buffered (both issued at iter top, drained by barrier A's
// implicit vmcnt(0) under QK+dist; barrier B is drain-free). Per-iter: P tile -> global Pws
// (bf16, coalesced full lines). Tail: complete-l reduction, O normalize + exp-map + hout,
// then read back own Pws tile (L2/L3-warm) and write normalized fp32 W coalesced.
// No register-held P (v4's spill failure mode), no partial-line W writes.
//
// LDS map (142336 B total):
//   Ks[2]  @      0 / 32768   (128 key-rows x 256B each, swizzle baked in Kb)
//   Vt[2]  @  65536 / 98304   (128 d-rows x 256B each, swizzle baked in Vtb)
//   Ps     @ 131072           (32 rows x 272B bf16)
//   yg[2]  @ 139776 / 140800  (128 float2 each: {yn, gy})
//   xr     @ 141824           (32 float2: {xn, rx})
//   l_row  @ 142080           (32 f32)
//   nsq_s  @ 142208           (32 f32)

__global__ __launch_bounds__(1024, 4) void hattn5_kernel(
    const unsigned short* __restrict__ Qb, const char* __restrict__ Kb, const char* __restrict__ Vtb,
    const float2* __restrict__ qng, const float2* __restrict__ kng,
    const float* __restrict__ cp, const float* __restrict__ betap, const float* __restrict__ biasp,
    uint4* __restrict__ Pws, float* __restrict__ hout, float* __restrict__ wout) {

    __shared__ __align__(1024) char smem[142336];
    char* PsB = smem + 131072;
    float* l_row = (float*)(smem + 142080);
    float* nsq_s = (float*)(smem + 142208);

    const int tid = threadIdx.x;
    const int lane = tid & 63, wave = tid >> 6;      // 16 waves
    const int wm = wave & 1, wn = wave >> 1;         // wm: 16-row half; wn: 16-col / 16-d slice (0..7)
    const int lm = lane & 15, quad = lane >> 4;

    int xcd = blockIdx.x & 7;                        // group batches per XCD for L2 locality
    int b = xcd >> 1;
    int rb = (blockIdx.x >> 3) * 2 + (xcd & 1);      // 0..63
    int s0 = rb * 32;
    const size_t bS = (size_t)b * S_;

    const float beta = betap[0], bias = biasp[0];
    const float cc = cp[0];
    const float beta_pos = fmaxf(beta, 0.f) + log1pf(__expf(-fabsf(beta)));
    const float sqrt_c = sqrtf(cc);
    const float bneg = -beta_pos / sqrt_c;           // p = 2^(bneg*log2(w) + bias2)
    const float bias2 = -bias * 1.442695040888963f;
    const float onepe = 1.f + EPSF;

    const char* KbBase = Kb + bS * 256;
    const char* VtBase = Vtb + (size_t)b * 16 * 32768;

    // ---- prologue: stage tile 0 into buffer 0 (full-wave gload_lds), tables via plain ops ----
    {
#pragma unroll
        for (int j = 0; j < 2; ++j) {
            int m = tid + j * 1024;
            gload_lds16(KbBase + m * 16, smem + m * 16);
            gload_lds16(VtBase + m * 16, smem + 65536 + m * 16);
        }
        if (tid < 128) {
            float2 y = kng[bS + tid];
            *(float2*)(smem + 139776 + tid * 8) = y;
        } else if (tid < 160) {
            float2 x = qng[bS + s0 + (tid - 128)];
            *(float2*)(smem + 141824 + (tid - 128) * 8) = x;
        } else if (tid < 192) {
            l_row[tid - 160] = 0.f;
        } else if (tid < 224) {
            nsq_s[tid - 192] = 0.f;
        }
    }

    // Q A-frags in registers (A: m=lane&15, k=quad*8+j)
    short8 aq[4];
    {
        const unsigned short* qrow = Qb + (bS + s0 + wm * 16 + lm) * D_;
#pragma unroll
        for (int ks = 0; ks < 4; ++ks)
            aq[ks] = *(const short8*)(qrow + ks * 32 + quad * 8);
    }

    f32x4 o = {0.f, 0.f, 0.f, 0.f};
    float lacc[4] = {0.f, 0.f, 0.f, 0.f};

    __syncthreads();   // prologue staging drained (vmcnt(0)+lgkmcnt(0) implicit)

    int p = 0;
    const int n0 = wn * 16 + lm;                     // key col (QK) / d index (PV)
    for (int it = 0; it < 16; ++it) {
        char* KsC = smem + p * 32768;
        char* VtC = smem + 65536 + p * 32768;
        const char* YGC = smem + 139776 + p * 1024;

        // ---- issue next K+V tiles into back buffers + kng load to regs (hidden under QK+dist) ----
        float2 ygn;
        if (it < 15) {
            const char* ks = KbBase + (size_t)(it + 1) * 32768;
            const char* vs = VtBase + (size_t)(it + 1) * 32768;
            char* kd = smem + (p ^ 1) * 32768;
            char* vd = smem + 65536 + (p ^ 1) * 32768;
#pragma unroll
            for (int j = 0; j < 2; ++j) {
                int off = (tid + j * 1024) * 16;
                gload_lds16(ks + off, kd + off);
                gload_lds16(vs + off, vd + off);
            }
            if (tid < 128) ygn = kng[bS + (size_t)(it + 1) * 128 + tid];
        }

        // ---- S = Q K^T (wave tile 16x16 of the 32x128 block tile) ----
        f32x4 acc = {0.f, 0.f, 0.f, 0.f};
#pragma unroll
        for (int ks = 0; ks < 4; ++ks) {
            int c = ks * 4 + quad;
            short8 bk = *(const short8*)(KsC + n0 * 256 + ((c ^ (n0 & 7)) * 16));
            acc = __builtin_amdgcn_mfma_f32_16x16x32_bf16(aq[ks], bk, acc, 0, 0, 0);
        }

        // ---- dist -> p = exp2(bneg*log2(arg+sqrt(arg^2-1)) + bias2), unnormalized ----
        {
            float2 yg = *(const float2*)(YGC + n0 * 8);
#pragma unroll
            for (int r = 0; r < 4; ++r) {
                int row = wm * 16 + quad * 4 + r;    // C/D layout: row=(lane>>4)*4+reg
                float2 xr = *(const float2*)(smem + 141824 + row * 8);
                float diff = fmaf(-2.f, acc[r], xr.x + yg.x);
                float arg = fmaf(diff * yg.y, xr.y, 1.f);
                arg = fmaxf(arg, onepe);
                float w = arg + sqrtf(fmaf(arg, arg, -1.f));
                float pv = __builtin_amdgcn_exp2f(fmaf(bneg, __builtin_amdgcn_logf(w), bias2));
                *(unsigned short*)(PsB + row * PSB + n0 * 2) = f2bf(pv);
                lacc[r] += pv;
            }
        }
        __syncthreads();   // A: Ps visible; K/V back buffers staged (implicit vmcnt drain)

        // ---- store next-iter key norms to back LDS table (visible after barrier B) ----
        if (it < 15 && tid < 128) *(float2*)(smem + 139776 + (p ^ 1) * 1024 + tid * 8) = ygn;

        // ---- coalesced P tile -> global bf16 (32x128 = 8KB = 512 x uint4, full lines) ----
        if (tid < 512) {
            int row = tid >> 4, ch = tid & 15;
            uint4 pv = *(const uint4*)(PsB + row * PSB + ch * 16);
            Pws[(((bS + s0 + row) * S_ + (size_t)it * 128) >> 3) + ch] = pv;
        }

        // ---- O += P V (wave tile 16 rows x 16 d, K=128 keys) ----
#pragma unroll
        for (int ks = 0; ks < 4; ++ks) {
            short8 ap = *(const short8*)(PsB + (wm * 16 + lm) * PSB + (ks * 32 + quad * 8) * 2);
            int c = ks * 4 + quad;
            short8 vv = *(const short8*)(VtC + n0 * 256 + ((c ^ (n0 & 7)) * 16));
            o = __builtin_amdgcn_mfma_f32_16x16x32_bf16(ap, vv, o, 0, 0, 0);
        }
        __syncthreads();   // B: Ps/Ks/Vt[p] readers done; yg store visible (drain-free)
        p ^= 1;
    }

    // ---- l reduction: per-thread register sums -> 16-lane shfl -> LDS atomics ----
#pragma unroll
    for (int r = 0; r < 4; ++r) {
        float s = lacc[r];
#pragma unroll
        for (int m = 1; m <= 8; m <<= 1) s += __shfl_xor(s, m, 64);
        if (lm == 0) atomicAdd(&l_row[wm * 16 + quad * 4 + r], s);
    }
    __syncthreads();

    float linv[4];
#pragma unroll
    for (int r = 0; r < 4; ++r) linv[r] = 1.f / l_row[wm * 16 + quad * 4 + r];

    // ---- O normalize + exp-map + hout ----
#pragma unroll
    for (int r = 0; r < 4; ++r) {
        float x = o[r] * linv[r];
        o[r] = x;
        float np = x * x;
#pragma unroll
        for (int m = 1; m <= 8; m <<= 1) np += __shfl_xor(np, m, 64);
        if (lm == 0) atomicAdd(&nsq_s[wm * 16 + quad * 4 + r], np);
    }
    __syncthreads();
#pragma unroll
    for (int r = 0; r < 4; ++r) {
        int row = wm * 16 + quad * 4 + r;
        float vn = fmaxf(sqrtf(nsq_s[row]), EPSF);
        float a = sqrt_c * vn;
        float th = 1.f - 2.f / (__expf(2.f * a) + 1.f);  // tanh(a)
        float sc = th / a;                                // tanh(sqrt_c*vn)/(sqrt_c*vn)
        hout[(bS + s0 + row) * D_ + n0] = o[r] * sc;
    }

    // ---- read back own Pws tile (L2/L3-warm) -> normalized fp32 W, fully coalesced ----
    {
        const uint4* psrc = Pws + (((bS + s0) * (size_t)S_) >> 3);
        float4* wdst = (float4*)(wout + (bS + s0) * (size_t)S_);
#pragma unroll
        for (int j = 0; j < 8; ++j) {
            int idx = tid + j * 1024;                // 8192 uint4 = 32 rows x 256
            int row = idx >> 8;
            float lr = 1.f / l_row[row];
            uint4 u = psrc[idx];
            float4 f0, f1;
            f0.x = __uint_as_float(u.x << 16) * lr;
            f0.y = __uint_as_float(u.x & 0xffff0000u) * lr;
            f0.z = __uint_as_float(u.y << 16) * lr;
            f0.w = __uint_as_float(u.y & 0xffff0000u) * lr;
            f1.x = __uint_as_float(u.z << 16) * lr;
            f1.y = __uint_as_float(u.z & 0xffff0000u) * lr;
            f1.z = __uint_as_float(u.w << 16) * lr;
            f1.w = __uint_as_float(u.w & 0xffff0000u) * lr;
            wdst[idx * 2] = f0;
            wdst[idx * 2 + 1] = f1;
        }
    }
}

// ===================== round-2 path (proven, ws fallback) =====================

__global__ __launch_bounds__(512, 2) void hattn_kernel(
    const unsigned short* __restrict__ Qb, const char* __restrict__ Kb, const char* __restrict__ Vtb,
    const float* __restrict__ qn, const float* __restrict__ kn,
    const float* __restrict__ cp, const float* __restrict__ betap, const float* __restrict__ biasp,
    float* __restrict__ lws, float* __restrict__ houtg, float* __restrict__ woutg) {

    __shared__ __align__(1024) char smem[75136];
    char* KsB = smem;
    char* VtB = smem + 32768;
    char* PsB = smem + 65536;
    float* kn_s  = (float*)(smem + 74240);
    float* qn_s  = (float*)(smem + 74752);
    float* l_row = (float*)(smem + 74880);
    float* nsq_s = (float*)(smem + 75008);

    const int tid = threadIdx.x;
    const int lane = tid & 63, wave = tid >> 6;
    const int wm = wave & 1, wn = wave >> 1;
    const int lm = lane & 15, quad = lane >> 4;

    int xcd = blockIdx.x & 7;
    int b = xcd >> 1;
    int rb = (blockIdx.x >> 3) * 2 + (xcd & 1);
    int s0 = rb * 32;
    const size_t bS = (size_t)b * S_;

    const float cc = cp[0], beta = betap[0], bias = biasp[0];
    const float beta_pos = fmaxf(beta, 0.f) + log1pf(__expf(-fabsf(beta)));
    const float sqrt_c = sqrtf(cc);
    const float inv_sqrt_c = 1.f / sqrt_c;

    if (tid < 32) {
        qn_s[tid] = qn[bS + s0 + tid];
        l_row[tid] = 0.f;
        nsq_s[tid] = 0.f;
    }

    short8 aq[4];
    {
        const unsigned short* qrow = Qb + (bS + s0 + wm * 16 + lm) * D_;
#pragma unroll
        for (int ks = 0; ks < 4; ++ks)
            aq[ks] = *(const short8*)(qrow + ks * 32 + quad * 8);
    }

    f32x4 o0 = {0.f, 0.f, 0.f, 0.f}, o1 = {0.f, 0.f, 0.f, 0.f};

    const char* KbBase = Kb + bS * 256;
    const char* VtBase = Vtb + (size_t)b * 16 * 32768;

    for (int t = 0; t < S_ / BN; ++t) {
        int t0 = t * BN;
        __syncthreads();
        {
            const uint4* ksrc = (const uint4*)(KbBase + (size_t)t0 * 256);
            const uint4* vsrc = (const uint4*)(VtBase + (size_t)t * 32768);
            uint4* kd = (uint4*)KsB;
            uint4* vd = (uint4*)VtB;
#pragma unroll
            for (int i = 0; i < 4; ++i) {
                kd[tid + i * 512] = ksrc[tid + i * 512];
                vd[tid + i * 512] = vsrc[tid + i * 512];
            }
            if (tid < BN) kn_s[tid] = kn[bS + t0 + tid];
        }
        __syncthreads();

        f32x4 acc0 = {0.f, 0.f, 0.f, 0.f}, acc1 = {0.f, 0.f, 0.f, 0.f};
#pragma unroll
        for (int ks = 0; ks < 4; ++ks) {
            int n0 = wn * 32 + lm;
            int c = ks * 4 + quad;
            short8 b0 = *(const short8*)(KsB + n0 * 256 + ((c ^ (n0 & 7)) * 16));
            int n1 = n0 + 16;
            short8 b1 = *(const short8*)(KsB + n1 * 256 + ((c ^ (n1 & 7)) * 16));
            acc0 = __builtin_amdgcn_mfma_f32_16x16x32_bf16(aq[ks], b0, acc0, 0, 0, 0);
            acc1 = __builtin_amdgcn_mfma_f32_16x16x32_bf16(aq[ks], b1, acc1, 0, 0, 0);
        }

        float lp[4];
#pragma unroll
        for (int r = 0; r < 4; ++r) {
            int row = wm * 16 + quad * 4 + r;
            float xn = qn_s[row];
            float fx = 1.f - cc * xn;
            float p0, p1;
#pragma unroll
            for (int nt = 0; nt < 2; ++nt) {
                int col = wn * 32 + nt * 16 + lm;
                float dot = (nt == 0) ? acc0[r] : acc1[r];
                float yn = kn_s[col];
                float diff = xn - 2.f * dot + yn;
                float den = fmaxf(fx * (1.f - cc * yn), EPSF);
                float arg = fmaf(2.f * cc * diff, __builtin_amdgcn_rcpf(den), 1.f);
                arg = fmaxf(arg, 1.f + EPSF);
                float dist = __logf(arg + sqrtf(arg * arg - 1.f)) * inv_sqrt_c;
                float p = __expf(fmaf(-beta_pos, dist, -bias));
                woutg[(bS + s0 + row) * S_ + t0 + col] = p;
                *(unsigned short*)(PsB + row * PSB + col * 2) = f2bf(p);
                if (nt == 0) p0 = p; else p1 = p;
            }
            lp[r] = p0 + p1;
        }
#pragma unroll
        for (int r = 0; r < 4; ++r) {
            float s = lp[r];
#pragma unroll
            for (int m = 1; m <= 8; m <<= 1) s += __shfl_xor(s, m, 64);
            if (lm == 0) atomicAdd(&l_row[wm * 16 + quad * 4 + r], s);
        }
        __syncthreads();

#pragma unroll
        for (int ks = 0; ks < 4; ++ks) {
            short8 ap = *(const short8*)(PsB + (wm * 16 + lm) * PSB + (ks * 32 + quad * 8) * 2);
            int d0 = wn * 32 + lm;
            int c = ks * 4 + quad;
            short8 v0 = *(const short8*)(VtB + d0 * 256 + ((c ^ (d0 & 7)) * 16));
            int d1 = d0 + 16;
            short8 v1 = *(const short8*)(VtB + d1 * 256 + ((c ^ (d1 & 7)) * 16));
            o0 = __builtin_amdgcn_mfma_f32_16x16x32_bf16(ap, v0, o0, 0, 0, 0);
            o1 = __builtin_amdgcn_mfma_f32_16x16x32_bf16(ap, v1, o1, 0, 0, 0);
        }
    }
    __syncthreads();

    float xs0[4], xs1[4];
#pragma unroll
    for (int r = 0; r < 4; ++r) {
        int row = wm * 16 + quad * 4 + r;
        float linv = __builtin_amdgcn_rcpf(l_row[row]);
        float x0 = o0[r] * linv, x1 = o1[r] * linv;
        xs0[r] = x0; xs1[r] = x1;
        float np = x0 * x0 + x1 * x1;
#pragma unroll
        for (int m = 1; m <= 8; m <<= 1) np += __shfl_xor(np, m, 64);
        if (lm == 0) atomicAdd(&nsq_s[row], np);
    }
    if (tid < 32) lws[bS + s0 + tid] = l_row[tid];
    __syncthreads();
#pragma unroll
    for (int r = 0; r < 4; ++r) {
        int row = wm * 16 + quad * 4 + r;
        float vn = fmaxf(sqrtf(nsq_s[row]), EPSF);
        float a = sqrt_c * vn;
        float th = 1.f - 2.f * __builtin_amdgcn_rcpf(__expf(2.f * a) + 1.f);
        float sc = th / a;
        houtg[(bS + s0 + row) * D_ + wn * 32 + lm] = xs0[r] * sc;
        houtg[(bS + s0 + row) * D_ + wn * 32 + 16 + lm] = xs1[r] * sc;
    }
}

__global__ __launch_bounds__(256) void wnorm_kernel(float* __restrict__ w,
                                                    const float* __restrict__ lws) {
    size_t idx = (size_t)blockIdx.x * 256 + threadIdx.x;
    int row = (int)(idx >> 9);
    float linv = 1.f / lws[row];
    float4* p = (float4*)w + idx;
    float4 v = *p;
    v.x *= linv; v.y *= linv; v.z *= linv; v.w *= linv;
    *p = v;
}

// ===================== launch =====================

extern "C" void kernel_launch(void* const* d_in, const int* in_sizes, int n_in,
                              void* d_out, int out_size, void* d_ws, size_t ws_size,
                              hipStream_t stream) {
    const float* q    = (const float*)d_in[0];
    const float* k    = (const float*)d_in[1];
    const float* v    = (const float*)d_in[2];
    const float* c    = (const float*)d_in[3];
    const float* beta = (const float*)d_in[4];
    const float* ab   = (const float*)d_in[5];

    float* out  = (float*)d_out;
    float* hout = out;                          // (B,S,D)
    float* wout = out + (size_t)B_ * S_ * D_;   // (B,S,S)

    float* qn  = (float*)d_ws;
    float* kn  = qn + B_ * S_;
    float* lws = kn + B_ * S_;
    char*  wsb = (char*)d_ws;
    const size_t QG_OFF = 98304;
    const size_t KG_OFF = QG_OFF + 65536;
    const size_t QB_OFF = KG_OFF + 65536;       // 229376
    const size_t KB_OFF = QB_OFF + 2097152;
    const size_t VT_OFF = KB_OFF + 2097152;
    const size_t NEED1  = VT_OFF + 2097152;
    const size_t PW_OFF = NEED1;
    const size_t NEED2  = PW_OFF + (size_t)B_ * S_ * S_ * 2;   // +33.5 MB bf16 P staging

    float2*  qng = (float2*)(wsb + QG_OFF);
    float2*  kng = (float2*)(wsb + KG_OFF);
    unsigned* Qb = (unsigned*)(wsb + QB_OFF);
    unsigned* Kb = (unsigned*)(wsb + KB_OFF);
    uint4*   Vtb = (uint4*)(wsb + VT_OFF);

    if (ws_size >= NEED2) {
        uint4* Pws = (uint4*)(wsb + PW_OFF);
        convqk_kernel<<<4096, 256, 0, stream>>>(q, k, c, qn, kn, lws, qng, kng, Qb, Kb);
        convv_kernel<<<64, 256, 0, stream>>>(v, Vtb);
        hattn5_kernel<<<256, 1024, 0, stream>>>((const unsigned short*)Qb, (const char*)Kb,
                                                (const char*)Vtb, qng, kng, c, beta, ab,
                                                Pws, hout, wout);
    } else {
        convqk_kernel<<<4096, 256, 0, stream>>>(q, k, c, qn, kn, lws, qng, kng, Qb, Kb);
        convv_kernel<<<64, 256, 0, stream>>>(v, Vtb);
        hattn_kernel<<<256, 512, 0, stream>>>((const unsigned short*)Qb, (const char*)Kb,
                                              (const char*)Vtb, qn, kn, c, beta, ab,
                                              lws, hout, wout);
        wnorm_kernel<<<(B_ * S_ * S_ / 4) / 256, 256, 0, stream>>>(wout, lws);
    }
}

// Round 5
// 137.423 us; speedup vs baseline: 1.0935x; 1.0743x over previous
//
#include <hip/hip_runtime.h>
#include <math.h>

#define B_ 4
#define S_ 2048
#define D_ 128
#define EPSF 1e-5f
#define BN 128
#define PSB 272     // fallback-path Ps row stride
#define PRS 4112    // v6 P_row stride bytes (2048*2 + 16): 16B-aligned, bank-shifted

typedef __attribute__((ext_vector_type(8))) short short8;
typedef __attribute__((ext_vector_type(4))) float f32x4;

static __device__ __forceinline__ unsigned short f2bf(float f) {
    unsigned u = __float_as_uint(f);
    return (unsigned short)((u + 0x7fffu + ((u >> 16) & 1u)) >> 16);
}

// ===================== pre-pass kernels (shared by both paths) =====================
// ws bytes: [0,32K) qn, [32K,64K) kn, [64K,96K) lws, [96K,160K) qng, [160K,224K) kng,
//           [224K..) Qb(2M) Kb(2M) Vtb(2M)

__global__ __launch_bounds__(256) void convqk_kernel(const float* __restrict__ q,
                                                     const float* __restrict__ k,
                                                     const float* __restrict__ cp,
                                                     float* __restrict__ qn, float* __restrict__ kn,
                                                     float* __restrict__ lws,
                                                     float2* __restrict__ qng, float2* __restrict__ kng,
                                                     unsigned* __restrict__ Qb, unsigned* __restrict__ Kb) {
    int row = blockIdx.x * 4 + (threadIdx.x >> 6);   // one wave per row, 16384 rows
    int lane = threadIdx.x & 63;
    const int NR = B_ * S_;
    const float cc = cp[0];
    bool isQ = row < NR;
    int r = isQ ? row : row - NR;
    float2 v = ((const float2*)(isQ ? q : k))[(size_t)r * 64 + lane];
    unsigned pk = (unsigned)f2bf(v.x) | ((unsigned)f2bf(v.y) << 16);
    float nrm = v.x * v.x + v.y * v.y;
#pragma unroll
    for (int m = 1; m <= 32; m <<= 1) nrm += __shfl_xor(nrm, m, 64);
    if (isQ) {
        Qb[(size_t)r * 64 + lane] = pk;              // plain row-major
        if (lane == 0) {
            qn[r] = nrm;
            qng[r] = make_float2(nrm, 2.f * cc * __builtin_amdgcn_rcpf(1.f - cc * nrm));
        }
        if (lane == 1) lws[r] = 0.f;                 // zero l accumulator (fallback path)
    } else {
        int c = lane >> 2;                           // 16B chunk index 0..15
        int cs = c ^ (r & 7);                        // bank swizzle baked into global layout
        Kb[(size_t)r * 64 + cs * 4 + (lane & 3)] = pk;
        if (lane == 0) {
            kn[r] = nrm;
            kng[r] = make_float2(nrm, __builtin_amdgcn_rcpf(1.f - cc * nrm));
        }
    }
}

__global__ __launch_bounds__(256) void convv_kernel(const float* __restrict__ v, uint4* __restrict__ Vtb) {
    __shared__ unsigned short Vs[128 * 132];
    int b = blockIdx.x >> 4;
    int t = blockIdx.x & 15;
    int tid = threadIdx.x;
    const float* src = v + ((size_t)b * S_ + t * 128) * D_;
    int d4 = tid & 31, key0 = tid >> 5;
#pragma unroll
    for (int it = 0; it < 16; ++it) {
        int key = key0 + it * 8;
        float4 f = *(const float4*)(src + (size_t)key * D_ + d4 * 4);
        unsigned short* dst = &Vs[key * 132 + d4 * 4];
        dst[0] = f2bf(f.x); dst[1] = f2bf(f.y); dst[2] = f2bf(f.z); dst[3] = f2bf(f.w);
    }
    __syncthreads();
    uint4* tile = Vtb + (size_t)blockIdx.x * (128 * 16);   // [tile][d=128][16 x 16B chunks]
    int d = tid & 127;
    int cl = tid >> 7;
#pragma unroll
    for (int it = 0; it < 8; ++it) {
        int c = cl + it * 2;
        int kb = c * 8;
        unsigned short e0 = Vs[(kb + 0) * 132 + d], e1 = Vs[(kb + 1) * 132 + d];
        unsigned short e2 = Vs[(kb + 2) * 132 + d], e3 = Vs[(kb + 3) * 132 + d];
        unsigned short e4 = Vs[(kb + 4) * 132 + d], e5 = Vs[(kb + 5) * 132 + d];
        unsigned short e6 = Vs[(kb + 6) * 132 + d], e7 = Vs[(kb + 7) * 132 + d];
        uint4 o;
        o.x = (unsigned)e0 | ((unsigned)e1 << 16);
        o.y = (unsigned)e2 | ((unsigned)e3 << 16);
        o.z = (unsigned)e4 | ((unsigned)e5 << 16);
        o.w = (unsigned)e6 | ((unsigned)e7 << 16);
        tile[d * 16 + (c ^ (d & 7))] = o;
    }
}

// ===================== v6: full-row P in LDS, K/V fragments direct from global =====================
// One 1024-thread block per 32 q-rows (grid 256, 1 block/CU, 16 waves). P for the whole row
// lives in LDS (32 x 2048 bf16, stride 4112B). K/V MFMA fragments are read straight from the
// pre-swizzled global Kb/Vtb (L2/L3-resident) into registers, software-pipelined: kf(it+1)+yg(it+1)
// issued after QK, vf(it) issued before the dist VALU chain -> all loads complete by the barrier.
// ONE barrier per iteration (each iter writes a disjoint 128-col P stripe; no WAR).
// Tail: l reduction -> O normalize + exp-map + hout -> P_lds -> normalized fp32 W (67 MB, once).
//
// LDS map (132096 B): P_row @0 (32 x 4112), xr @131584 (32 float2), l_row @131840, nsq_s @131968.

__global__ __launch_bounds__(1024, 4) void hattn6_kernel(
    const unsigned short* __restrict__ Qb, const char* __restrict__ Kb, const char* __restrict__ Vtb,
    const float2* __restrict__ qng, const float2* __restrict__ kng,
    const float* __restrict__ cp, const float* __restrict__ betap, const float* __restrict__ biasp,
    float* __restrict__ hout, float* __restrict__ wout) {

    __shared__ __align__(1024) char smem[132096];
    float* l_row = (float*)(smem + 131840);
    float* nsq_s = (float*)(smem + 131968);

    const int tid = threadIdx.x;
    const int lane = tid & 63, wave = tid >> 6;      // 16 waves
    const int wm = wave & 1, wn = wave >> 1;         // wm: 16-row half; wn: 16-col/16-d slice (0..7)
    const int lm = lane & 15, quad = lane >> 4;

    int xcd = blockIdx.x & 7;                        // batches grouped per XCD for L2 locality
    int b = xcd >> 1;
    int rb = (blockIdx.x >> 3) * 2 + (xcd & 1);      // 0..63
    int s0 = rb * 32;
    const size_t bS = (size_t)b * S_;

    const float beta = betap[0], bias = biasp[0];
    const float cc = cp[0];
    const float beta_pos = fmaxf(beta, 0.f) + log1pf(__expf(-fabsf(beta)));
    const float sqrt_c = sqrtf(cc);
    const float bneg = -beta_pos / sqrt_c;           // p = 2^(bneg*log2(w) + bias2)
    const float bias2 = -bias * 1.442695040888963f;
    const float onepe = 1.f + EPSF;

    const char* KbBase = Kb + bS * 256;
    const char* VtBase = Vtb + (size_t)b * 16 * 32768;

    // ---- prologue: tables to LDS; issue K frags + key norms for tile 0 ----
    if (tid < 32) {
        float2 x = qng[bS + s0 + tid];
        *(float2*)(smem + 131584 + tid * 8) = x;
    } else if (tid < 64) {
        l_row[tid - 32] = 0.f;
    } else if (tid < 96) {
        nsq_s[tid - 64] = 0.f;
    }

    const int n0 = wn * 16 + lm;                     // key col (QK) / d index (PV)
    short8 kf[4];
    float2 yg;
    {
        const char* kb0 = KbBase + n0 * 256;
#pragma unroll
        for (int ks = 0; ks < 4; ++ks) {
            int c = ks * 4 + quad;
            kf[ks] = *(const short8*)(kb0 + ((c ^ (n0 & 7)) * 16));
        }
        yg = kng[bS + n0];
    }

    // Q A-frags in registers (A: m=lane&15, k=quad*8+j)
    short8 aq[4];
    {
        const unsigned short* qrow = Qb + (bS + s0 + wm * 16 + lm) * D_;
#pragma unroll
        for (int ks = 0; ks < 4; ++ks)
            aq[ks] = *(const short8*)(qrow + ks * 32 + quad * 8);
    }

    __syncthreads();   // tables visible

    // per-row constants, hoisted out of the loop
    float2 xr4[4];
#pragma unroll
    for (int r = 0; r < 4; ++r)
        xr4[r] = *(const float2*)(smem + 131584 + (wm * 16 + quad * 4 + r) * 8);

    f32x4 o = {0.f, 0.f, 0.f, 0.f};
    float lacc[4] = {0.f, 0.f, 0.f, 0.f};

    for (int it = 0; it < 16; ++it) {
        // ---- S = Q K^T (wave tile 16x16) ----
        f32x4 acc = {0.f, 0.f, 0.f, 0.f};
#pragma unroll
        for (int ks = 0; ks < 4; ++ks)
            acc = __builtin_amdgcn_mfma_f32_16x16x32_bf16(aq[ks], kf[ks], acc, 0, 0, 0);

        // ---- issue next-tile K frags + key norms (hidden under dist + PV) ----
        short8 kfn[4];
        float2 ygn;
        if (it < 15) {
            const char* kb = KbBase + (size_t)(it + 1) * 32768 + n0 * 256;
#pragma unroll
            for (int ks = 0; ks < 4; ++ks) {
                int c = ks * 4 + quad;
                kfn[ks] = *(const short8*)(kb + ((c ^ (n0 & 7)) * 16));
            }
            ygn = kng[bS + (size_t)(it + 1) * 128 + n0];
        }

        // ---- issue current-tile V frags (hidden under dist VALU) ----
        short8 vf[4];
        {
            const char* vb = VtBase + (size_t)it * 32768 + n0 * 256;
#pragma unroll
            for (int ks = 0; ks < 4; ++ks) {
                int c = ks * 4 + quad;
                vf[ks] = *(const short8*)(vb + ((c ^ (n0 & 7)) * 16));
            }
        }

        // ---- dist -> p = exp2(bneg*log2(arg+sqrt(arg^2-1)) + bias2), unnormalized ----
#pragma unroll
        for (int r = 0; r < 4; ++r) {
            int row = wm * 16 + quad * 4 + r;        // C/D layout: row=(lane>>4)*4+reg
            float diff = fmaf(-2.f, acc[r], xr4[r].x + yg.x);
            float arg = fmaf(diff * yg.y, xr4[r].y, 1.f);
            arg = fmaxf(arg, onepe);
            float w = arg + sqrtf(fmaf(arg, arg, -1.f));
            float pv = __builtin_amdgcn_exp2f(fmaf(bneg, __builtin_amdgcn_logf(w), bias2));
            *(unsigned short*)(smem + row * PRS + (it * 128 + n0) * 2) = f2bf(pv);
            lacc[r] += pv;
        }
        __syncthreads();   // P stripe visible (loads already near-complete -> cheap drain)

        // ---- O += P V (wave tile 16 rows x 16 d, K=128 keys) ----
        {
            const char* prow = smem + (wm * 16 + lm) * PRS + it * 256 + quad * 16;
#pragma unroll
            for (int ks = 0; ks < 4; ++ks) {
                short8 ap = *(const short8*)(prow + ks * 64);
                o = __builtin_amdgcn_mfma_f32_16x16x32_bf16(ap, vf[ks], o, 0, 0, 0);
            }
        }

        if (it < 15) {
#pragma unroll
            for (int ks = 0; ks < 4; ++ks) kf[ks] = kfn[ks];
            yg = ygn;
        }
    }

    // ---- l reduction: per-thread register sums -> 16-lane shfl -> LDS atomics ----
#pragma unroll
    for (int r = 0; r < 4; ++r) {
        float s = lacc[r];
#pragma unroll
        for (int m = 1; m <= 8; m <<= 1) s += __shfl_xor(s, m, 64);
        if (lm == 0) atomicAdd(&l_row[wm * 16 + quad * 4 + r], s);
    }
    __syncthreads();

    float linv[4];
#pragma unroll
    for (int r = 0; r < 4; ++r) linv[r] = 1.f / l_row[wm * 16 + quad * 4 + r];

    // ---- O normalize + exp-map + hout ----
#pragma unroll
    for (int r = 0; r < 4; ++r) {
        float x = o[r] * linv[r];
        o[r] = x;
        float np = x * x;
#pragma unroll
        for (int m = 1; m <= 8; m <<= 1) np += __shfl_xor(np, m, 64);
        if (lm == 0) atomicAdd(&nsq_s[wm * 16 + quad * 4 + r], np);
    }
    __syncthreads();
#pragma unroll
    for (int r = 0; r < 4; ++r) {
        int row = wm * 16 + quad * 4 + r;
        float vn = fmaxf(sqrtf(nsq_s[row]), EPSF);
        float a = sqrt_c * vn;
        float th = 1.f - 2.f / (__expf(2.f * a) + 1.f);  // tanh(a)
        float sc = th / a;                                // tanh(sqrt_c*vn)/(sqrt_c*vn)
        hout[(bS + s0 + row) * D_ + n0] = o[r] * sc;
    }

    // ---- P_lds -> normalized fp32 W, single coalesced write (32 x 2048 = 256 KB/block) ----
    {
        float4* wdst = (float4*)(wout + (bS + s0) * (size_t)S_);
#pragma unroll
        for (int j = 0; j < 8; ++j) {
            int idx = tid + j * 1024;                // 8192 chunks = 32 rows x 256
            int row = idx >> 8;
            int ch = idx & 255;
            float lr = 1.f / l_row[row];
            uint4 u = *(const uint4*)(smem + row * PRS + ch * 16);
            float4 f0, f1;
            f0.x = __uint_as_float(u.x << 16) * lr;
            f0.y = __uint_as_float(u.x & 0xffff0000u) * lr;
            f0.z = __uint_as_float(u.y << 16) * lr;
            f0.w = __uint_as_float(u.y & 0xffff0000u) * lr;
            f1.x = __uint_as_float(u.z << 16) * lr;
            f1.y = __uint_as_float(u.z & 0xffff0000u) * lr;
            f1.z = __uint_as_float(u.w << 16) * lr;
            f1.w = __uint_as_float(u.w & 0xffff0000u) * lr;
            wdst[idx * 2] = f0;
            wdst[idx * 2 + 1] = f1;
        }
    }
}

// ===================== round-2 path (proven, ws fallback) =====================

__global__ __launch_bounds__(512, 2) void hattn_kernel(
    const unsigned short* __restrict__ Qb, const char* __restrict__ Kb, const char* __restrict__ Vtb,
    const float* __restrict__ qn, const float* __restrict__ kn,
    const float* __restrict__ cp, const float* __restrict__ betap, const float* __restrict__ biasp,
    float* __restrict__ lws, float* __restrict__ houtg, float* __restrict__ woutg) {

    __shared__ __align__(1024) char smem[75136];
    char* KsB = smem;
    char* VtB = smem + 32768;
    char* PsB = smem + 65536;
    float* kn_s  = (float*)(smem + 74240);
    float* qn_s  = (float*)(smem + 74752);
    float* l_row = (float*)(smem + 74880);
    float* nsq_s = (float*)(smem + 75008);

    const int tid = threadIdx.x;
    const int lane = tid & 63, wave = tid >> 6;
    const int wm = wave & 1, wn = wave >> 1;
    const int lm = lane & 15, quad = lane >> 4;

    int xcd = blockIdx.x & 7;
    int b = xcd >> 1;
    int rb = (blockIdx.x >> 3) * 2 + (xcd & 1);
    int s0 = rb * 32;
    const size_t bS = (size_t)b * S_;

    const float cc = cp[0], beta = betap[0], bias = biasp[0];
    const float beta_pos = fmaxf(beta, 0.f) + log1pf(__expf(-fabsf(beta)));
    const float sqrt_c = sqrtf(cc);
    const float inv_sqrt_c = 1.f / sqrt_c;

    if (tid < 32) {
        qn_s[tid] = qn[bS + s0 + tid];
        l_row[tid] = 0.f;
        nsq_s[tid] = 0.f;
    }

    short8 aq[4];
    {
        const unsigned short* qrow = Qb + (bS + s0 + wm * 16 + lm) * D_;
#pragma unroll
        for (int ks = 0; ks < 4; ++ks)
            aq[ks] = *(const short8*)(qrow + ks * 32 + quad * 8);
    }

    f32x4 o0 = {0.f, 0.f, 0.f, 0.f}, o1 = {0.f, 0.f, 0.f, 0.f};

    const char* KbBase = Kb + bS * 256;
    const char* VtBase = Vtb + (size_t)b * 16 * 32768;

    for (int t = 0; t < S_ / BN; ++t) {
        int t0 = t * BN;
        __syncthreads();
        {
            const uint4* ksrc = (const uint4*)(KbBase + (size_t)t0 * 256);
            const uint4* vsrc = (const uint4*)(VtBase + (size_t)t * 32768);
            uint4* kd = (uint4*)KsB;
            uint4* vd = (uint4*)VtB;
#pragma unroll
            for (int i = 0; i < 4; ++i) {
                kd[tid + i * 512] = ksrc[tid + i * 512];
                vd[tid + i * 512] = vsrc[tid + i * 512];
            }
            if (tid < BN) kn_s[tid] = kn[bS + t0 + tid];
        }
        __syncthreads();

        f32x4 acc0 = {0.f, 0.f, 0.f, 0.f}, acc1 = {0.f, 0.f, 0.f, 0.f};
#pragma unroll
        for (int ks = 0; ks < 4; ++ks) {
            int n0 = wn * 32 + lm;
            int c = ks * 4 + quad;
            short8 b0 = *(const short8*)(KsB + n0 * 256 + ((c ^ (n0 & 7)) * 16));
            int n1 = n0 + 16;
            short8 b1 = *(const short8*)(KsB + n1 * 256 + ((c ^ (n1 & 7)) * 16));
            acc0 = __builtin_amdgcn_mfma_f32_16x16x32_bf16(aq[ks], b0, acc0, 0, 0, 0);
            acc1 = __builtin_amdgcn_mfma_f32_16x16x32_bf16(aq[ks], b1, acc1, 0, 0, 0);
        }

        float lp[4];
#pragma unroll
        for (int r = 0; r < 4; ++r) {
            int row = wm * 16 + quad * 4 + r;
            float xn = qn_s[row];
            float fx = 1.f - cc * xn;
            float p0, p1;
#pragma unroll
            for (int nt = 0; nt < 2; ++nt) {
                int col = wn * 32 + nt * 16 + lm;
                float dot = (nt == 0) ? acc0[r] : acc1[r];
                float yn = kn_s[col];
                float diff = xn - 2.f * dot + yn;
                float den = fmaxf(fx * (1.f - cc * yn), EPSF);
                float arg = fmaf(2.f * cc * diff, __builtin_amdgcn_rcpf(den), 1.f);
                arg = fmaxf(arg, 1.f + EPSF);
                float dist = __logf(arg + sqrtf(arg * arg - 1.f)) * inv_sqrt_c;
                float p = __expf(fmaf(-beta_pos, dist, -bias));
                woutg[(bS + s0 + row) * S_ + t0 + col] = p;
                *(unsigned short*)(PsB + row * PSB + col * 2) = f2bf(p);
                if (nt == 0) p0 = p; else p1 = p;
            }
            lp[r] = p0 + p1;
        }
#pragma unroll
        for (int r = 0; r < 4; ++r) {
            float s = lp[r];
#pragma unroll
            for (int m = 1; m <= 8; m <<= 1) s += __shfl_xor(s, m, 64);
            if (lm == 0) atomicAdd(&l_row[wm * 16 + quad * 4 + r], s);
        }
        __syncthreads();

#pragma unroll
        for (int ks = 0; ks < 4; ++ks) {
            short8 ap = *(const short8*)(PsB + (wm * 16 + lm) * PSB + (ks * 32 + quad * 8) * 2);
            int d0 = wn * 32 + lm;
            int c = ks * 4 + quad;
            short8 v0 = *(const short8*)(VtB + d0 * 256 + ((c ^ (d0 & 7)) * 16));
            int d1 = d0 + 16;
            short8 v1 = *(const short8*)(VtB + d1 * 256 + ((c ^ (d1 & 7)) * 16));
            o0 = __builtin_amdgcn_mfma_f32_16x16x32_bf16(ap, v0, o0, 0, 0, 0);
            o1 = __builtin_amdgcn_mfma_f32_16x16x32_bf16(ap, v1, o1, 0, 0, 0);
        }
    }
    __syncthreads();

    float xs0[4], xs1[4];
#pragma unroll
    for (int r = 0; r < 4; ++r) {
        int row = wm * 16 + quad * 4 + r;
        float linv = __builtin_amdgcn_rcpf(l_row[row]);
        float x0 = o0[r] * linv, x1 = o1[r] * linv;
        xs0[r] = x0; xs1[r] = x1;
        float np = x0 * x0 + x1 * x1;
#pragma unroll
        for (int m = 1; m <= 8; m <<= 1) np += __shfl_xor(np, m, 64);
        if (lm == 0) atomicAdd(&nsq_s[row], np);
    }
    if (tid < 32) lws[bS + s0 + tid] = l_row[tid];
    __syncthreads();
#pragma unroll
    for (int r = 0; r < 4; ++r) {
        int row = wm * 16 + quad * 4 + r;
        float vn = fmaxf(sqrtf(nsq_s[row]), EPSF);
        float a = sqrt_c * vn;
        float th = 1.f - 2.f * __builtin_amdgcn_rcpf(__expf(2.f * a) + 1.f);
        float sc = th / a;
        houtg[(bS + s0 + row) * D_ + wn * 32 + lm] = xs0[r] * sc;
        houtg[(bS + s0 + row) * D_ + wn * 32 + 16 + lm] = xs1[r] * sc;
    }
}

__global__ __launch_bounds__(256) void wnorm_kernel(float* __restrict__ w,
                                                    const float* __restrict__ lws) {
    size_t idx = (size_t)blockIdx.x * 256 + threadIdx.x;
    int row = (int)(idx >> 9);
    float linv = 1.f / lws[row];
    float4* p = (float4*)w + idx;
    float4 v = *p;
    v.x *= linv; v.y *= linv; v.z *= linv; v.w *= linv;
    *p = v;
}

// ===================== launch =====================

extern "C" void kernel_launch(void* const* d_in, const int* in_sizes, int n_in,
                              void* d_out, int out_size, void* d_ws, size_t ws_size,
                              hipStream_t stream) {
    const float* q    = (const float*)d_in[0];
    const float* k    = (const float*)d_in[1];
    const float* v    = (const float*)d_in[2];
    const float* c    = (const float*)d_in[3];
    const float* beta = (const float*)d_in[4];
    const float* ab   = (const float*)d_in[5];

    float* out  = (float*)d_out;
    float* hout = out;                          // (B,S,D)
    float* wout = out + (size_t)B_ * S_ * D_;   // (B,S,S)

    float* qn  = (float*)d_ws;
    float* kn  = qn + B_ * S_;
    float* lws = kn + B_ * S_;
    char*  wsb = (char*)d_ws;
    const size_t QG_OFF = 98304;
    const size_t KG_OFF = QG_OFF + 65536;
    const size_t QB_OFF = KG_OFF + 65536;       // 229376
    const size_t KB_OFF = QB_OFF + 2097152;
    const size_t VT_OFF = KB_OFF + 2097152;
    const size_t NEED1  = VT_OFF + 2097152;

    float2*  qng = (float2*)(wsb + QG_OFF);
    float2*  kng = (float2*)(wsb + KG_OFF);
    unsigned* Qb = (unsigned*)(wsb + QB_OFF);
    unsigned* Kb = (unsigned*)(wsb + KB_OFF);
    uint4*   Vtb = (uint4*)(wsb + VT_OFF);

    if (ws_size >= NEED1) {
        convqk_kernel<<<4096, 256, 0, stream>>>(q, k, c, qn, kn, lws, qng, kng, Qb, Kb);
        convv_kernel<<<64, 256, 0, stream>>>(v, Vtb);
        hattn6_kernel<<<256, 1024, 0, stream>>>((const unsigned short*)Qb, (const char*)Kb,
                                                (const char*)Vtb, qng, kng, c, beta, ab,
                                                hout, wout);
    } else {
        convqk_kernel<<<4096, 256, 0, stream>>>(q, k, c, qn, kn, lws, qng, kng, Qb, Kb);
        convv_kernel<<<64, 256, 0, stream>>>(v, Vtb);
        hattn_kernel<<<256, 512, 0, stream>>>((const unsigned short*)Qb, (const char*)Kb,
                                              (const char*)Vtb, qn, kn, c, beta, ab,
                                              lws, hout, wout);
        wnorm_kernel<<<(B_ * S_ * S_ / 4) / 256, 256, 0, stream>>>(wout, lws);
    }
}